// Round 1
// baseline (1557.099 us; speedup 1.0000x reference)
//
#include <hip/hip_runtime.h>

#define NN 100000
#define EE 1600000
#define FIN 128
#define HH 64
#define CC 40

// deg[i] = 1 (self-loop)
__global__ void k_deg_init(float* __restrict__ deg) {
  int i = blockIdx.x * blockDim.x + threadIdx.x;
  if (i < NN) deg[i] = 1.0f;
}

// deg[dst] += 1 per edge
__global__ void k_deg(const int* __restrict__ dst, float* __restrict__ deg) {
  int e = blockIdx.x * blockDim.x + threadIdx.x;
  if (e < EE) atomicAdd(&deg[dst[e]], 1.0f);
}

// dinv = rsqrt(deg), in place (deg >= 1 always)
__global__ void k_rsqrt(float* __restrict__ deg) {
  int i = blockIdx.x * blockDim.x + threadIdx.x;
  if (i < NN) deg[i] = rsqrtf(deg[i]);
}

// h[N,64] = x[N,128] @ W[128,64]. Lane owns output column; W column kept in
// 128 VGPRs; x row read as broadcast float4 (1 load / 4 FMA).
__global__ void k_gemm1(const float* __restrict__ x, const float* __restrict__ W,
                        float* __restrict__ h) {
  const int lane = threadIdx.x & 63;
  float w[FIN];
#pragma unroll
  for (int k = 0; k < FIN; ++k) w[k] = W[k * HH + lane];
  int wid = blockIdx.x * (blockDim.x >> 6) + (threadIdx.x >> 6);
  int nw  = gridDim.x * (blockDim.x >> 6);
  for (int row = wid; row < NN; row += nw) {
    const float4* xr = reinterpret_cast<const float4*>(x + (size_t)row * FIN);
    float a0 = 0.f, a1 = 0.f, a2 = 0.f, a3 = 0.f;
#pragma unroll
    for (int k4 = 0; k4 < FIN / 4; ++k4) {
      float4 xv = xr[k4];
      a0 += xv.x * w[4 * k4 + 0];
      a1 += xv.y * w[4 * k4 + 1];
      a2 += xv.z * w[4 * k4 + 2];
      a3 += xv.w * w[4 * k4 + 3];
    }
    h[(size_t)row * HH + lane] = (a0 + a1) + (a2 + a3);
  }
}

// wave per edge: acc[dst][lane] += h[src][lane] * dinv[src]*dinv[dst]
__global__ void k_scatter1(const int* __restrict__ ei, const float* __restrict__ h,
                           const float* __restrict__ dinv, float* __restrict__ acc) {
  const int lane = threadIdx.x & 63;
  int wid = blockIdx.x * (blockDim.x >> 6) + (threadIdx.x >> 6);
  int nw  = gridDim.x * (blockDim.x >> 6);
  for (int e = wid; e < EE; e += nw) {
    int s = ei[e];
    int d = ei[EE + e];
    float nrm = dinv[s] * dinv[d];
    float v = h[(size_t)s * HH + lane] * nrm;
    atomicAdd(&acc[(size_t)d * HH + lane], v);
  }
}

// h1 = relu(acc + h*dinv^2 + b1), in place over acc
__global__ void k_relu(const float* __restrict__ h, const float* __restrict__ dinv,
                       const float* __restrict__ b1, float* __restrict__ acc) {
  size_t stride = (size_t)gridDim.x * blockDim.x;
  for (size_t i = (size_t)blockIdx.x * blockDim.x + threadIdx.x; i < (size_t)NN * HH;
       i += stride) {
    int row = (int)(i >> 6);
    int c   = (int)(i & 63);
    float di = dinv[row];
    float v  = acc[i] + h[i] * di * di + b1[c];
    acc[i]   = v > 0.f ? v : 0.f;
  }
}

// h2[N,40] = h1[N,64] @ W2[64,40]; lanes >= 40 idle on store
__global__ void k_gemm2(const float* __restrict__ h1, const float* __restrict__ W,
                        float* __restrict__ h2) {
  const int lane = threadIdx.x & 63;
  float w[HH];
  if (lane < CC) {
#pragma unroll
    for (int k = 0; k < HH; ++k) w[k] = W[k * CC + lane];
  } else {
#pragma unroll
    for (int k = 0; k < HH; ++k) w[k] = 0.f;
  }
  int wid = blockIdx.x * (blockDim.x >> 6) + (threadIdx.x >> 6);
  int nw  = gridDim.x * (blockDim.x >> 6);
  for (int row = wid; row < NN; row += nw) {
    const float4* xr = reinterpret_cast<const float4*>(h1 + (size_t)row * HH);
    float a0 = 0.f, a1 = 0.f, a2 = 0.f, a3 = 0.f;
#pragma unroll
    for (int k4 = 0; k4 < HH / 4; ++k4) {
      float4 xv = xr[k4];
      a0 += xv.x * w[4 * k4 + 0];
      a1 += xv.y * w[4 * k4 + 1];
      a2 += xv.z * w[4 * k4 + 2];
      a3 += xv.w * w[4 * k4 + 3];
    }
    if (lane < CC) h2[(size_t)row * CC + lane] = (a0 + a1) + (a2 + a3);
  }
}

// wave per edge: out[dst][c] += h2[src][c] * norm, c < 40
__global__ void k_scatter2(const int* __restrict__ ei, const float* __restrict__ h2,
                           const float* __restrict__ dinv, float* __restrict__ out) {
  const int lane = threadIdx.x & 63;
  int wid = blockIdx.x * (blockDim.x >> 6) + (threadIdx.x >> 6);
  int nw  = gridDim.x * (blockDim.x >> 6);
  for (int e = wid; e < EE; e += nw) {
    int s = ei[e];
    int d = ei[EE + e];
    float nrm = dinv[s] * dinv[d];
    if (lane < CC) {
      float v = h2[(size_t)s * CC + lane] * nrm;
      atomicAdd(&out[(size_t)d * CC + lane], v);
    }
  }
}

// out = log_softmax(out + h2*dinv^2 + b2) per row, wave per node
__global__ void k_final(const float* __restrict__ h2, const float* __restrict__ dinv,
                        const float* __restrict__ b2, float* __restrict__ out) {
  const int lane = threadIdx.x & 63;
  int wid = blockIdx.x * (blockDim.x >> 6) + (threadIdx.x >> 6);
  int nw  = gridDim.x * (blockDim.x >> 6);
  for (int i = wid; i < NN; i += nw) {
    float di = dinv[i];
    bool act = lane < CC;
    float v = act ? (out[(size_t)i * CC + lane] + h2[(size_t)i * CC + lane] * di * di + b2[lane])
                  : -__builtin_inff();
    float m = v;
#pragma unroll
    for (int off = 32; off > 0; off >>= 1) m = fmaxf(m, __shfl_xor(m, off));
    float ex = act ? expf(v - m) : 0.f;
    float s = ex;
#pragma unroll
    for (int off = 32; off > 0; off >>= 1) s += __shfl_xor(s, off);
    if (act) out[(size_t)i * CC + lane] = v - m - logf(s);
  }
}

extern "C" void kernel_launch(void* const* d_in, const int* in_sizes, int n_in,
                              void* d_out, int out_size, void* d_ws, size_t ws_size,
                              hipStream_t stream) {
  const float* x  = (const float*)d_in[0];
  const int*   ei = (const int*)d_in[1];
  const float* W1 = (const float*)d_in[2];
  const float* b1 = (const float*)d_in[3];
  const float* W2 = (const float*)d_in[4];
  const float* b2 = (const float*)d_in[5];
  float* out = (float*)d_out;

  float* dinv = (float*)d_ws;               // N
  float* hbuf = dinv + NN;                  // N*64 (h; later h2 as N*40)
  float* acc  = hbuf + (size_t)NN * HH;     // N*64 (acc1; then h1 in place)

  hipMemsetAsync(acc, 0, (size_t)NN * HH * sizeof(float), stream);
  hipMemsetAsync(out, 0, (size_t)NN * CC * sizeof(float), stream);

  k_deg_init<<<(NN + 255) / 256, 256, 0, stream>>>(dinv);
  k_deg<<<(EE + 255) / 256, 256, 0, stream>>>(ei + EE, dinv);
  k_rsqrt<<<(NN + 255) / 256, 256, 0, stream>>>(dinv);

  k_gemm1<<<1024, 256, 0, stream>>>(x, W1, hbuf);
  k_scatter1<<<4096, 256, 0, stream>>>(ei, hbuf, dinv, acc);
  k_relu<<<2048, 256, 0, stream>>>(hbuf, dinv, b1, acc);
  k_gemm2<<<1024, 256, 0, stream>>>(acc, W2, hbuf);
  k_scatter2<<<4096, 256, 0, stream>>>(ei, hbuf, dinv, out);
  k_final<<<(NN * 64 + 255) / 256, 256, 0, stream>>>(hbuf, dinv, b2, out);
}

// Round 3
// 999.250 us; speedup vs baseline: 1.5583x; 1.5583x over previous
//
#include <hip/hip_runtime.h>

#define NN 100000
#define EE 1600000
#define FIN 128
#define HH 64
#define CC 40

// deg[i] = 1 (self-loop)
__global__ void k_deg_init(float* __restrict__ deg) {
  int i = blockIdx.x * blockDim.x + threadIdx.x;
  if (i < NN) deg[i] = 1.0f;
}

// deg[dst] += 1 per edge
__global__ void k_deg(const int* __restrict__ dst, float* __restrict__ deg) {
  int e = blockIdx.x * blockDim.x + threadIdx.x;
  if (e < EE) atomicAdd(&deg[dst[e]], 1.0f);
}

// dinv = rsqrt(deg), in place (deg >= 1 always)
__global__ void k_rsqrt(float* __restrict__ deg) {
  int i = blockIdx.x * blockDim.x + threadIdx.x;
  if (i < NN) deg[i] = rsqrtf(deg[i]);
}

// h[N,64] = x[N,128] @ W[128,64]. Lane owns output column; W column kept in
// 128 VGPRs (launch_bounds(256,1) -> up to 512 VGPR, no spill); x row read as
// broadcast float4 (1 load / 4 FMA).
__global__ void __launch_bounds__(256, 1)
k_gemm1(const float* __restrict__ x, const float* __restrict__ W,
        float* __restrict__ h) {
  const int lane = threadIdx.x & 63;
  float w[FIN];
#pragma unroll
  for (int k = 0; k < FIN; ++k) w[k] = W[k * HH + lane];
  int wid = blockIdx.x * (blockDim.x >> 6) + (threadIdx.x >> 6);
  int nw  = gridDim.x * (blockDim.x >> 6);
  for (int row = wid; row < NN; row += nw) {
    const float4* xr = reinterpret_cast<const float4*>(x + (size_t)row * FIN);
    float a0 = 0.f, a1 = 0.f, a2 = 0.f, a3 = 0.f;
#pragma unroll
    for (int k4 = 0; k4 < FIN / 4; ++k4) {
      float4 xv = xr[k4];
      a0 += xv.x * w[4 * k4 + 0];
      a1 += xv.y * w[4 * k4 + 1];
      a2 += xv.z * w[4 * k4 + 2];
      a3 += xv.w * w[4 * k4 + 3];
    }
    h[(size_t)row * HH + lane] = (a0 + a1) + (a2 + a3);
  }
}

// wave per edge: acc[dst][lane] += h[src][lane] * dinv[src]*dinv[dst]
__global__ void k_scatter1(const int* __restrict__ ei, const float* __restrict__ h,
                           const float* __restrict__ dinv, float* __restrict__ acc) {
  const int lane = threadIdx.x & 63;
  int wid = blockIdx.x * (blockDim.x >> 6) + (threadIdx.x >> 6);
  int nw  = gridDim.x * (blockDim.x >> 6);
  for (int e = wid; e < EE; e += nw) {
    int s = ei[e];
    int d = ei[EE + e];
    float nrm = dinv[s] * dinv[d];
    float v = h[(size_t)s * HH + lane] * nrm;
    atomicAdd(&acc[(size_t)d * HH + lane], v);
  }
}

// h1 = relu(acc + h*dinv^2 + b1), in place over acc
__global__ void k_relu(const float* __restrict__ h, const float* __restrict__ dinv,
                       const float* __restrict__ b1, float* __restrict__ acc) {
  size_t stride = (size_t)gridDim.x * blockDim.x;
  for (size_t i = (size_t)blockIdx.x * blockDim.x + threadIdx.x; i < (size_t)NN * HH;
       i += stride) {
    int row = (int)(i >> 6);
    int c   = (int)(i & 63);
    float di = dinv[row];
    float v  = acc[i] + h[i] * di * di + b1[c];
    acc[i]   = v > 0.f ? v : 0.f;
  }
}

// h2[N,40] = h1[N,64] @ W2[64,40]; lanes >= 40 idle on store
__global__ void __launch_bounds__(256, 1)
k_gemm2(const float* __restrict__ h1, const float* __restrict__ W,
        float* __restrict__ h2) {
  const int lane = threadIdx.x & 63;
  float w[HH];
  if (lane < CC) {
#pragma unroll
    for (int k = 0; k < HH; ++k) w[k] = W[k * CC + lane];
  } else {
#pragma unroll
    for (int k = 0; k < HH; ++k) w[k] = 0.f;
  }
  int wid = blockIdx.x * (blockDim.x >> 6) + (threadIdx.x >> 6);
  int nw  = gridDim.x * (blockDim.x >> 6);
  for (int row = wid; row < NN; row += nw) {
    const float4* xr = reinterpret_cast<const float4*>(h1 + (size_t)row * HH);
    float a0 = 0.f, a1 = 0.f, a2 = 0.f, a3 = 0.f;
#pragma unroll
    for (int k4 = 0; k4 < HH / 4; ++k4) {
      float4 xv = xr[k4];
      a0 += xv.x * w[4 * k4 + 0];
      a1 += xv.y * w[4 * k4 + 1];
      a2 += xv.z * w[4 * k4 + 2];
      a3 += xv.w * w[4 * k4 + 3];
    }
    if (lane < CC) h2[(size_t)row * CC + lane] = (a0 + a1) + (a2 + a3);
  }
}

// wave per edge: out[dst][c] += h2[src][c] * norm, c < 40
__global__ void k_scatter2(const int* __restrict__ ei, const float* __restrict__ h2,
                           const float* __restrict__ dinv, float* __restrict__ out) {
  const int lane = threadIdx.x & 63;
  int wid = blockIdx.x * (blockDim.x >> 6) + (threadIdx.x >> 6);
  int nw  = gridDim.x * (blockDim.x >> 6);
  for (int e = wid; e < EE; e += nw) {
    int s = ei[e];
    int d = ei[EE + e];
    float nrm = dinv[s] * dinv[d];
    if (lane < CC) {
      float v = h2[(size_t)s * CC + lane] * nrm;
      atomicAdd(&out[(size_t)d * CC + lane], v);
    }
  }
}

// out = log_softmax(out + h2*dinv^2 + b2) per row, wave per node
__global__ void k_final(const float* __restrict__ h2, const float* __restrict__ dinv,
                        const float* __restrict__ b2, float* __restrict__ out) {
  const int lane = threadIdx.x & 63;
  int wid = blockIdx.x * (blockDim.x >> 6) + (threadIdx.x >> 6);
  int nw  = gridDim.x * (blockDim.x >> 6);
  for (int i = wid; i < NN; i += nw) {
    float di = dinv[i];
    bool act = lane < CC;
    float v = act ? (out[(size_t)i * CC + lane] + h2[(size_t)i * CC + lane] * di * di + b2[lane])
                  : -__builtin_inff();
    float m = v;
#pragma unroll
    for (int off = 32; off > 0; off >>= 1) m = fmaxf(m, __shfl_xor(m, off));
    float ex = act ? expf(v - m) : 0.f;
    float s = ex;
#pragma unroll
    for (int off = 32; off > 0; off >>= 1) s += __shfl_xor(s, off);
    if (act) out[(size_t)i * CC + lane] = v - m - logf(s);
  }
}

extern "C" void kernel_launch(void* const* d_in, const int* in_sizes, int n_in,
                              void* d_out, int out_size, void* d_ws, size_t ws_size,
                              hipStream_t stream) {
  const float* x  = (const float*)d_in[0];
  const int*   ei = (const int*)d_in[1];
  const float* W1 = (const float*)d_in[2];
  const float* b1 = (const float*)d_in[3];
  const float* W2 = (const float*)d_in[4];
  const float* b2 = (const float*)d_in[5];
  float* out = (float*)d_out;

  float* dinv = (float*)d_ws;               // N
  float* hbuf = dinv + NN;                  // N*64 (h; later h2 as N*40)
  float* acc  = hbuf + (size_t)NN * HH;     // N*64 (acc1; then h1 in place)

  hipMemsetAsync(acc, 0, (size_t)NN * HH * sizeof(float), stream);
  hipMemsetAsync(out, 0, (size_t)NN * CC * sizeof(float), stream);

  k_deg_init<<<(NN + 255) / 256, 256, 0, stream>>>(dinv);
  k_deg<<<(EE + 255) / 256, 256, 0, stream>>>(ei + EE, dinv);
  k_rsqrt<<<(NN + 255) / 256, 256, 0, stream>>>(dinv);

  k_gemm1<<<1024, 256, 0, stream>>>(x, W1, hbuf);
  k_scatter1<<<4096, 256, 0, stream>>>(ei, hbuf, dinv, acc);
  k_relu<<<2048, 256, 0, stream>>>(hbuf, dinv, b1, acc);
  k_gemm2<<<1024, 256, 0, stream>>>(acc, W2, hbuf);
  k_scatter2<<<4096, 256, 0, stream>>>(ei, hbuf, dinv, out);
  k_final<<<(NN * 64 + 255) / 256, 256, 0, stream>>>(hbuf, dinv, b2, out);
}

// Round 4
// 730.623 us; speedup vs baseline: 2.1312x; 1.3677x over previous
//
#include <hip/hip_runtime.h>

#define NN 100000
#define EE 1600000
#define FIN 128
#define HH 64
#define CC 40
#define NB 98  // ceil(NN/1024) scan blocks

// ---- CSR build -------------------------------------------------------------
// rp holds counts at rp[1+d] (rp[0]=0 from memset), scanned in place.

__global__ void k_count(const int* __restrict__ dst, int* __restrict__ rp) {
  int e = blockIdx.x * blockDim.x + threadIdx.x;
  if (e < EE) atomicAdd(&rp[1 + dst[e]], 1);
}

// per-block inclusive scan of rp[1..NN]; also dinv[i] = rsqrt(cnt+1)
__global__ void __launch_bounds__(1024)
k_scan_a(int* __restrict__ rp, float* __restrict__ dinv, int* __restrict__ bsum) {
  __shared__ int sm[1024];
  int i = blockIdx.x * 1024 + threadIdx.x;
  int c = (i < NN) ? rp[i + 1] : 0;
  if (i < NN) dinv[i] = rsqrtf((float)(c + 1));
  sm[threadIdx.x] = c;
  __syncthreads();
#pragma unroll
  for (int off = 1; off < 1024; off <<= 1) {
    int v = (threadIdx.x >= off) ? sm[threadIdx.x - off] : 0;
    __syncthreads();
    sm[threadIdx.x] += v;
    __syncthreads();
  }
  if (i < NN) rp[i + 1] = sm[threadIdx.x];
  if (threadIdx.x == 1023) bsum[blockIdx.x] = sm[1023];
}

// exclusive scan of the NB block sums (single block)
__global__ void __launch_bounds__(128)
k_scan_b(int* __restrict__ bsum) {
  __shared__ int sm[128];
  int v = (threadIdx.x < NB) ? bsum[threadIdx.x] : 0;
  sm[threadIdx.x] = v;
  __syncthreads();
#pragma unroll
  for (int off = 1; off < 128; off <<= 1) {
    int u = (threadIdx.x >= off) ? sm[threadIdx.x - off] : 0;
    __syncthreads();
    sm[threadIdx.x] += u;
    __syncthreads();
  }
  bsum[threadIdx.x] = sm[threadIdx.x] - v;  // exclusive
}

__global__ void k_scan_c(int* __restrict__ rp, const int* __restrict__ bsum) {
  int i = blockIdx.x * blockDim.x + threadIdx.x;
  if (i < NN) rp[i + 1] += bsum[i >> 10];
}

// col[pos] = src, pos = wp[dst]++
__global__ void k_fill(const int* __restrict__ ei, int* __restrict__ wp,
                       int* __restrict__ col) {
  int e = blockIdx.x * blockDim.x + threadIdx.x;
  if (e < EE) {
    int s = ei[e];
    int d = ei[EE + e];
    int pos = atomicAdd(&wp[d], 1);
    col[pos] = s;
  }
}

// ---- layer compute ---------------------------------------------------------

// hs[N,64] = dinv[row] * (x[N,128] @ W[128,64]). Lane owns output column; W
// column in 128 VGPRs (launch_bounds(256,1) -> no spill).
__global__ void __launch_bounds__(256, 1)
k_gemm1(const float* __restrict__ x, const float* __restrict__ W,
        const float* __restrict__ dinv, float* __restrict__ hs) {
  const int lane = threadIdx.x & 63;
  float w[FIN];
#pragma unroll
  for (int k = 0; k < FIN; ++k) w[k] = W[k * HH + lane];
  int wid = blockIdx.x * (blockDim.x >> 6) + (threadIdx.x >> 6);
  int nw  = gridDim.x * (blockDim.x >> 6);
  for (int row = wid; row < NN; row += nw) {
    const float4* xr = reinterpret_cast<const float4*>(x + (size_t)row * FIN);
    float a0 = 0.f, a1 = 0.f, a2 = 0.f, a3 = 0.f;
#pragma unroll
    for (int k4 = 0; k4 < FIN / 4; ++k4) {
      float4 xv = xr[k4];
      a0 += xv.x * w[4 * k4 + 0];
      a1 += xv.y * w[4 * k4 + 1];
      a2 += xv.z * w[4 * k4 + 2];
      a3 += xv.w * w[4 * k4 + 3];
    }
    hs[(size_t)row * HH + lane] = ((a0 + a1) + (a2 + a3)) * dinv[row];
  }
}

// wave per node: h1[d] = relu(dinv[d] * (hs[d] + sum_{s in N(d)} hs[s]) + b1)
__global__ void __launch_bounds__(256)
k_agg1(const int* __restrict__ rp, const int* __restrict__ col,
       const float* __restrict__ hs, const float* __restrict__ dinv,
       const float* __restrict__ b1, float* __restrict__ h1) {
  const int lane = threadIdx.x & 63;
  int d = blockIdx.x * 4 + (threadIdx.x >> 6);
  if (d >= NN) return;
  int e   = rp[d];
  int end = rp[d + 1];
  float acc = hs[(size_t)d * HH + lane];
  for (; e + 1 < end; e += 2) {
    int s0 = col[e], s1 = col[e + 1];
    acc += hs[(size_t)s0 * HH + lane];
    acc += hs[(size_t)s1 * HH + lane];
  }
  if (e < end) acc += hs[(size_t)col[e] * HH + lane];
  float v = acc * dinv[d] + b1[lane];
  h1[(size_t)d * HH + lane] = v > 0.f ? v : 0.f;
}

// hs2[N,40] = dinv[row] * (h1[N,64] @ W2[64,40])
__global__ void __launch_bounds__(256, 1)
k_gemm2(const float* __restrict__ h1, const float* __restrict__ W,
        const float* __restrict__ dinv, float* __restrict__ hs2) {
  const int lane = threadIdx.x & 63;
  float w[HH];
  if (lane < CC) {
#pragma unroll
    for (int k = 0; k < HH; ++k) w[k] = W[k * CC + lane];
  } else {
#pragma unroll
    for (int k = 0; k < HH; ++k) w[k] = 0.f;
  }
  int wid = blockIdx.x * (blockDim.x >> 6) + (threadIdx.x >> 6);
  int nw  = gridDim.x * (blockDim.x >> 6);
  for (int row = wid; row < NN; row += nw) {
    const float4* xr = reinterpret_cast<const float4*>(h1 + (size_t)row * HH);
    float a0 = 0.f, a1 = 0.f, a2 = 0.f, a3 = 0.f;
#pragma unroll
    for (int k4 = 0; k4 < HH / 4; ++k4) {
      float4 xv = xr[k4];
      a0 += xv.x * w[4 * k4 + 0];
      a1 += xv.y * w[4 * k4 + 1];
      a2 += xv.z * w[4 * k4 + 2];
      a3 += xv.w * w[4 * k4 + 3];
    }
    if (lane < CC) hs2[(size_t)row * CC + lane] = ((a0 + a1) + (a2 + a3)) * dinv[row];
  }
}

// wave per node: v = dinv[d]*(hs2[d]+sum hs2[s]) + b2; out = log_softmax(v)
__global__ void __launch_bounds__(256)
k_agg2(const int* __restrict__ rp, const int* __restrict__ col,
       const float* __restrict__ hs2, const float* __restrict__ dinv,
       const float* __restrict__ b2, float* __restrict__ out) {
  const int lane = threadIdx.x & 63;
  int d = blockIdx.x * 4 + (threadIdx.x >> 6);
  if (d >= NN) return;
  const bool act = lane < CC;
  int e   = rp[d];
  int end = rp[d + 1];
  float acc = act ? hs2[(size_t)d * CC + lane] : 0.f;
  for (; e + 1 < end; e += 2) {
    int s0 = col[e], s1 = col[e + 1];
    if (act) {
      acc += hs2[(size_t)s0 * CC + lane];
      acc += hs2[(size_t)s1 * CC + lane];
    }
  }
  if (e < end && act) acc += hs2[(size_t)col[e] * CC + lane];
  float v = act ? acc * dinv[d] + b2[lane] : -__builtin_inff();
  float m = v;
#pragma unroll
  for (int off = 32; off > 0; off >>= 1) m = fmaxf(m, __shfl_xor(m, off));
  float ex = act ? expf(v - m) : 0.f;
  float s = ex;
#pragma unroll
  for (int off = 32; off > 0; off >>= 1) s += __shfl_xor(s, off);
  if (act) out[(size_t)d * CC + lane] = v - m - logf(s);
}

extern "C" void kernel_launch(void* const* d_in, const int* in_sizes, int n_in,
                              void* d_out, int out_size, void* d_ws, size_t ws_size,
                              hipStream_t stream) {
  const float* x  = (const float*)d_in[0];
  const int*   ei = (const int*)d_in[1];
  const float* W1 = (const float*)d_in[2];
  const float* b1 = (const float*)d_in[3];
  const float* W2 = (const float*)d_in[4];
  const float* b2 = (const float*)d_in[5];
  float* out = (float*)d_out;

  // workspace layout (all 4-byte elems)
  float* dinv = (float*)d_ws;                    // NN
  int*   rp   = (int*)(dinv + NN);               // NN+1
  int*   wp   = rp + NN + 1;                     // NN
  int*   bsum = wp + NN;                         // 128
  int*   col  = bsum + 128;                      // EE
  float* hsA  = (float*)(col + EE);              // NN*64 (hs, then hs2 as NN*40)
  float* h1   = hsA + (size_t)NN * HH;           // NN*64
  // total ~58.9 MB

  hipMemsetAsync(rp, 0, (NN + 1) * sizeof(int), stream);

  k_count<<<(EE + 255) / 256, 256, 0, stream>>>(ei + EE, rp);
  k_scan_a<<<NB, 1024, 0, stream>>>(rp, dinv, bsum);
  k_scan_b<<<1, 128, 0, stream>>>(bsum);
  k_scan_c<<<(NN + 255) / 256, 256, 0, stream>>>(rp, bsum);
  hipMemcpyAsync(wp, rp, NN * sizeof(int), hipMemcpyDeviceToDevice, stream);
  k_fill<<<(EE + 255) / 256, 256, 0, stream>>>(ei, wp, col);

  k_gemm1<<<1024, 256, 0, stream>>>(x, W1, dinv, hsA);
  k_agg1<<<(NN + 3) / 4, 256, 0, stream>>>(rp, col, hsA, dinv, b1, h1);
  k_gemm2<<<1024, 256, 0, stream>>>(h1, W2, dinv, hsA);
  k_agg2<<<(NN + 3) / 4, 256, 0, stream>>>(rp, col, hsA, dinv, b2, out);
}